// Round 3
// baseline (640.348 us; speedup 1.0000x reference)
//
#include <hip/hip_runtime.h>

#define ROWSB 32
#define HIDN 256
#define TT 8
#define EPSI 1e-6f
#define HAS 260      // ha row stride (floats); 260%8=4 rotates bank groups per row
#define SVS 260      // sorted-vocab row stride in ws (257 used + 3 INF pad)
#define TBSTR 40
#define NCELL 512
#define WS_LUT_F   (32*SVS)                 // ushort lut[32][512] == 8192 floats
#define WS_DINFO_F (32*SVS + 8192)          // float2 dinfo[32] (base, scale)

__device__ __forceinline__ void ld4(float* d, const float* p) {
  float4 v = *(const float4*)p;
  d[0] = v.x; d[1] = v.y; d[2] = v.z; d[3] = v.w;
}

// ---------- pre-pass: per-dim bitonic sort of vocab + lower-bound LUT ----------
__global__ __launch_bounds__(256)
void sort_vocab(const float* __restrict__ vocab, float* __restrict__ ws) {
  __shared__ float arr[512];
  const int d = blockIdx.x;
  const int t = threadIdx.x;
  arr[t] = (t < 257) ? vocab[t*32 + d] : 3.0e38f;
  arr[t+256] = (t == 0) ? vocab[256*32 + d] : 3.0e38f;
  __syncthreads();
  for (int k = 2; k <= 512; k <<= 1) {
    for (int j = k >> 1; j > 0; j >>= 1) {
      #pragma unroll
      for (int h = 0; h < 2; ++h) {
        int i = t + h*256;
        int ixj = i ^ j;
        if (ixj > i) {
          float a = arr[i], b = arr[ixj];
          bool up = ((i & k) == 0);
          if ((a > b) == up) { arr[i] = b; arr[ixj] = a; }
        }
      }
      __syncthreads();
    }
  }
  #pragma unroll
  for (int h = 0; h < 2; ++h) {
    int i = t + h*256;
    if (i < SVS) ws[d*SVS + i] = (i < 257) ? arr[i] : 3.0e38f;
  }
  float base = arr[0];
  float maxv = arr[256];
  float scale = (float)NCELL / fmaxf(maxv - base, 1e-30f);
  if (t == 0) {
    float2* dinfo = (float2*)(ws + WS_DINFO_F);
    dinfo[d] = make_float2(base, scale);
  }
  #pragma unroll
  for (int h = 0; h < 2; ++h) {
    int cell = t + h*256;
    float target = base + (float)cell * (maxv - base) * (1.0f/(float)NCELL);
    int lo = 0, hi = 257;
    while (lo < hi) { int mid = (lo+hi)>>1; if (arr[mid] < target) lo = mid+1; else hi = mid; }
    ((unsigned short*)(ws + WS_LUT_F))[d*NCELL + cell] = (unsigned short)lo;
  }
}

// ---------- main fused kernel ----------
__global__ __launch_bounds__(256, 3)
void mac_fused(const float* __restrict__ hs, const float* __restrict__ eps,
               const float* __restrict__ WQ, const float* __restrict__ bQ,
               const float* __restrict__ WK, const float* __restrict__ bK,
               const float* __restrict__ Wmu, const float* __restrict__ bmu,
               const float* __restrict__ Wvar, const float* __restrict__ bvar,
               const float* __restrict__ vocab,
               const float* __restrict__ Wsum, const float* __restrict__ bsum,
               const float* __restrict__ Whead, const float* __restrict__ bhead,
               const float* __restrict__ ws, float* __restrict__ out, int Btot)
{
  // 38,656 B LDS -> up to 4 blocks/CU
  __shared__ __align__(16) float ha[ROWSB*HAS];       // wave-private rows; start: hs stage; end: comm/o1 alias
  __shared__ __align__(16) float tokbuf[ROWSB*TBSTR]; // wave-private
  __shared__ float ivbuf[ROWSB], finbuf[ROWSB];       // wave-private rows

  const int t   = threadIdx.x;
  const int c4  = t & 63;
  const int w   = t >> 6;         // wave id == row-octet == agent group
  const int sr  = t >> 3;         // sampling row (0..31); stays in wave's octet
  const int sc8 = t & 7;          // sampling dim-quad
  const int d0u = (c4 << 2) & 31;
  const int tg  = c4 >> 3;        // token slot of this thread's cols
  const int rowbase = blockIdx.x * ROWSB;

  float Qr[8][4], Vr[8][4], Kr[8][4], MSGr[8][4];
  float eosv[4];
  unsigned fin = 0u;

  // ---------------- staging (all wave-private) ----------------
  {
    const float* hp = hs + (size_t)(rowbase + w*8)*HIDN + c4*4;
    #pragma unroll
    for (int rr = 0; rr < 8; ++rr)
      *(float4*)&ha[(w*8+rr)*HAS + c4*4] = *(const float4*)(hp + (size_t)rr*HIDN);
  }
  if (c4 < 8) finbuf[w*8 + c4] = 0.f;
  ld4(eosv, vocab + 256*32 + d0u);
  {
    float bq[4], bk[4];
    ld4(bq, bQ + c4*4); ld4(bk, bK + c4*4);
    #pragma unroll
    for (int rr = 0; rr < 8; ++rr) {
      #pragma unroll
      for (int k = 0; k < 4; ++k) { Qr[rr][k] = bq[k]; Vr[rr][k] = bk[k]; }
    }
  }
  float dbr[4], dsr[4];
  {
    float t0[4], t1[4];
    ld4(t0, ws + WS_DINFO_F + sc8*8);
    ld4(t1, ws + WS_DINFO_F + sc8*8 + 4);
    dbr[0]=t0[0]; dsr[0]=t0[1]; dbr[1]=t0[2]; dsr[1]=t0[3];
    dbr[2]=t1[0]; dsr[2]=t1[1]; dbr[3]=t1[2]; dsr[3]=t1[3];
  }
  float bm[4], bv[4];
  ld4(bm, bmu + sc8*4); ld4(bv, bvar + sc8*4);
  __threadfence_block();   // own-wave ha(hs)/finbuf writes visible cross-lane

  // ------------- initial GEMM: Q = hs@WQ + bQ ; V = hs@WK + bK -------------
  #pragma unroll 2
  for (int jq = 0; jq < 64; ++jq) {
    float hsq[8][4];
    #pragma unroll
    for (int rr = 0; rr < 8; ++rr) ld4(hsq[rr], &ha[(w*8+rr)*HAS + jq*4]);
    #pragma unroll
    for (int m = 0; m < 4; ++m) {
      float wq[4], wk[4];
      ld4(wq, WQ + (size_t)(jq*4+m)*HIDN + c4*4);
      ld4(wk, WK + (size_t)(jq*4+m)*HIDN + c4*4);
      #pragma unroll
      for (int rr = 0; rr < 8; ++rr) {
        #pragma unroll
        for (int k = 0; k < 4; ++k) {
          Qr[rr][k] += hsq[rr][m]*wq[k];
          Vr[rr][k] += hsq[rr][m]*wk[k];
        }
      }
    }
  }
  {
    float bk[4]; ld4(bk, bK + c4*4);
    #pragma unroll
    for (int rr = 0; rr < 8; ++rr) {
      #pragma unroll
      for (int k = 0; k < 4; ++k) {
        Qr[rr][k] *= (1.0f/256.0f);   // bake NF^2: logit = -(Qr*Kr)
        Kr[rr][k]   = bk[k];
        MSGr[rr][k] = 0.f;
      }
    }
  }

  // ---------------- token recurrence (zero block barriers; waves skew) ----------------
  for (int it = 0; it < TT; ++it) {
    if (it > 0) {
      const float* Wr = WK + (size_t)((it-1)*32)*HIDN + c4*4;
      #pragma unroll 2
      for (int cq = 0; cq < 8; ++cq) {
        float tq[8][4];
        #pragma unroll
        for (int rr = 0; rr < 8; ++rr) ld4(tq[rr], &tokbuf[(w*8+rr)*TBSTR + cq*4]);
        #pragma unroll
        for (int m = 0; m < 4; ++m) {
          float wv[4]; ld4(wv, Wr + (size_t)(cq*4+m)*HIDN);
          #pragma unroll
          for (int rr = 0; rr < 8; ++rr) {
            #pragma unroll
            for (int k = 0; k < 4; ++k) Kr[rr][k] += tq[rr][m]*wv[k];
          }
        }
      }
    }

    // --- softmax(-(Q*K)) without max-sub (|logit|<~2e-3); store e*V; 1/s in ivbuf ---
    #pragma unroll
    for (int rr = 0; rr < 8; ++rr) {
      float e[4]; float s = 0.f;
      #pragma unroll
      for (int k = 0; k < 4; ++k) { e[k] = __expf(-(Qr[rr][k]*Kr[rr][k])); s += e[k]; }
      #pragma unroll
      for (int off = 32; off >= 1; off >>= 1) s += __shfl_xor(s, off);
      if (c4 == rr) ivbuf[w*8+rr] = 1.0f / s;
      *(float4*)&ha[(w*8+rr)*HAS + c4*4] =
          make_float4(e[0]*Vr[rr][0], e[1]*Vr[rr][1], e[2]*Vr[rr][2], e[3]*Vr[rr][3]);
    }
    __threadfence_block();

    // --- fused GEMV + sample + quantize: thread = (row sr, dims 4*sc8..+3) ---
    {
      float muv[4] = {0,0,0,0}, lvv[4] = {0,0,0,0};
      const float* wmp = Wmu + sc8*4;
      const float* wvp = Wvar + sc8*4;
      const float* harow = &ha[sr*HAS];
      #pragma unroll 2
      for (int jq = 0; jq < 64; ++jq) {
        float wm[4][4], wv2[4][4], h[4];
        #pragma unroll
        for (int m = 0; m < 4; ++m) ld4(wm[m],  wmp + (size_t)(jq*4+m)*32);
        #pragma unroll
        for (int m = 0; m < 4; ++m) ld4(wv2[m], wvp + (size_t)(jq*4+m)*32);
        ld4(h, harow + jq*4);
        #pragma unroll
        for (int m = 0; m < 4; ++m) {
          #pragma unroll
          for (int k = 0; k < 4; ++k) { muv[k] += h[m]*wm[m][k]; lvv[k] += h[m]*wv2[m][k]; }
        }
      }
      float ivr = ivbuf[sr];
      float msk = 1.0f - finbuf[sr];
      float ep[4]; ld4(ep, eps + ((size_t)it*Btot + rowbase + sr)*32 + sc8*4);
      const unsigned short* lutg = (const unsigned short*)(ws + WS_LUT_F);
      float md[4];
      #pragma unroll
      for (int k = 0; k < 4; ++k) {
        float mu = muv[k]*ivr + bm[k];
        float lv = lvv[k]*ivr + bv[k];
        float x  = ep[k]*__expf(0.5f*lv) + mu;
        int dim = sc8*4 + k;
        int c = (int)((x - dbr[k]) * dsr[k]);
        c = min(max(c, 0), NCELL-1);
        int idx = (int)lutg[dim*NCELL + c];
        const float* sp = ws + dim*SVS;
        float v = sp[idx];
        while (v < x) { ++idx; v = sp[idx]; }   // pads +INF -> terminates
        float dn = v - x;
        float dp = (idx > 0) ? (x - sp[idx-1]) : 3.0e38f;
        md[k] = fminf(dn, dp);
      }
      *(float4*)&tokbuf[sr*TBSTR + sc8*4] =
          make_float4(md[0]*md[0]*msk, md[1]*md[1]*msk, md[2]*md[2]*msk, md[3]*md[3]*msk);
    }
    __threadfence_block();

    // --- hit detection + message update ---
    {
      float tokr[8][4];
      #pragma unroll
      for (int rr = 0; rr < 8; ++rr) ld4(tokr[rr], &tokbuf[(w*8+rr)*TBSTR + d0u]);
      unsigned newfin = fin;
      #pragma unroll
      for (int rr = 0; rr < 8; ++rr) {
        float pd = 0.f, ed = 0.f;
        #pragma unroll
        for (int k = 0; k < 4; ++k) { float dm = tokr[rr][k]-MSGr[rr][k]; pd += dm*dm; }
        if (tg == 0) {
          #pragma unroll
          for (int k = 0; k < 4; ++k) { float de = tokr[rr][k]-eosv[k]; ed += de*de; }
        }
        pd += __shfl_xor(pd, 1); ed += __shfl_xor(ed, 1);
        pd += __shfl_xor(pd, 2); ed += __shfl_xor(ed, 2);
        pd += __shfl_xor(pd, 4); ed += __shfl_xor(ed, 4);
        bool lane_hit = (tg < it && pd < EPSI) || (tg == 0 && ed < EPSI);
        bool hit = (__ballot(lane_hit) != 0ull);
        if (hit) {
          if ((tg == it) && !((fin >> rr) & 1u)) {
            #pragma unroll
            for (int k = 0; k < 4; ++k) tokr[rr][k] = eosv[k];
          }
          newfin |= (1u << rr);
        }
        if (tg == it) {
          #pragma unroll
          for (int k = 0; k < 4; ++k) MSGr[rr][k] = tokr[rr][k];
        }
      }
      if (tg == it) {
        #pragma unroll
        for (int rr = 0; rr < 8; ++rr)
          *(float4*)&tokbuf[(w*8+rr)*TBSTR + d0u] =
              make_float4(MSGr[rr][0], MSGr[rr][1], MSGr[rr][2], MSGr[rr][3]);
      }
      if (c4 == 0) {
        #pragma unroll
        for (int rr = 0; rr < 8; ++rr)
          finbuf[w*8+rr] = ((newfin >> rr) & 1u) ? 1.f : 0.f;
      }
      fin = newfin;
    }
    __threadfence_block();
  }

  // ---------------- final: comm sum + two block-coop GEMVs + relu ----------------
  __syncthreads();                 // all waves done with ha before aliasing
  float* commb = ha;               // [4][HAS]
  float* o1    = ha + 4*HAS;       // [4][HAS]
  {
    float cs[4] = {0,0,0,0};
    #pragma unroll
    for (int rr = 0; rr < 8; ++rr) {
      #pragma unroll
      for (int k = 0; k < 4; ++k) cs[k] += MSGr[rr][k];
    }
    const float i7 = 1.0f/7.0f;
    *(float4*)&commb[w*HAS + c4*4] = make_float4(cs[0]*i7, cs[1]*i7, cs[2]*i7, cs[3]*i7);
  }
  __syncthreads();
  {
    float bs = bsum[t];
    float a1[4] = {bs, bs, bs, bs};
    #pragma unroll 2
    for (int jq = 0; jq < 64; ++jq) {
      float w4[4];
      #pragma unroll
      for (int m = 0; m < 4; ++m) w4[m] = Wsum[(size_t)(jq*4+m)*HIDN + t];
      #pragma unroll
      for (int g = 0; g < 4; ++g) {
        float c[4]; ld4(c, &commb[g*HAS + jq*4]);   // uniform broadcast
        a1[g] += c[0]*w4[0] + c[1]*w4[1] + c[2]*w4[2] + c[3]*w4[3];
      }
    }
    #pragma unroll
    for (int g = 0; g < 4; ++g) o1[g*HAS + t] = a1[g];
  }
  __syncthreads();
  {
    float bh = bhead[t];
    float a2[4] = {bh, bh, bh, bh};
    #pragma unroll 2
    for (int jq = 0; jq < 64; ++jq) {
      float w4[4];
      #pragma unroll
      for (int m = 0; m < 4; ++m) w4[m] = Whead[(size_t)(jq*4+m)*HIDN + t];
      #pragma unroll
      for (int g = 0; g < 4; ++g) {
        float c[4]; ld4(c, &o1[g*HAS + jq*4]);
        a2[g] += c[0]*w4[0] + c[1]*w4[1] + c[2]*w4[2] + c[3]*w4[3];
      }
    }
    #pragma unroll
    for (int g = 0; g < 4; ++g) {
      float r = fmaxf(a2[g], 0.f);
      #pragma unroll
      for (int rr = 0; rr < 8; ++rr)
        out[(size_t)(rowbase + g*8 + rr)*HIDN + t] = r;
    }
  }
}

extern "C" void kernel_launch(void* const* d_in, const int* in_sizes, int n_in,
                              void* d_out, int out_size, void* d_ws, size_t ws_size,
                              hipStream_t stream) {
    const float* hs    = (const float*)d_in[0];
    const float* eps   = (const float*)d_in[1];
    const float* WQ    = (const float*)d_in[2];
    const float* bQ    = (const float*)d_in[3];
    const float* WK    = (const float*)d_in[4];
    const float* bK    = (const float*)d_in[5];
    const float* Wmu   = (const float*)d_in[6];
    const float* bmu   = (const float*)d_in[7];
    const float* Wvar  = (const float*)d_in[8];
    const float* bvar  = (const float*)d_in[9];
    const float* vocab = (const float*)d_in[10];
    const float* Wsum  = (const float*)d_in[11];
    const float* bsum  = (const float*)d_in[12];
    const float* Whead = (const float*)d_in[13];
    const float* bhead = (const float*)d_in[14];
    float* o = (float*)d_out;
    float* wsf = (float*)d_ws;
    int Btot = in_sizes[0] / HIDN;
    hipLaunchKernelGGL(sort_vocab, dim3(32), dim3(256), 0, stream, vocab, wsf);
    hipLaunchKernelGGL(mac_fused, dim3(Btot / ROWSB), dim3(256), 0, stream,
                       hs, eps, WQ, bQ, WK, bK, Wmu, bmu, Wvar, bvar,
                       vocab, Wsum, bsum, Whead, bhead, wsf, o, Btot);
}